// Round 9
// baseline (152.956 us; speedup 1.0000x reference)
//
#include <hip/hip_runtime.h>
#include <hip/hip_bf16.h>
#include <hip/hip_cooperative_groups.h>

namespace cg = cooperative_groups;

#define BATCH 64
#define NADJ  512
#define F     128
#define CROP0 128
#define CROP1 384
#define CN    256
#define BN_EPS 1e-5f

typedef __attribute__((ext_vector_type(8))) short short8;
typedef __attribute__((ext_vector_type(4))) float f32x4;

__device__ __forceinline__ ushort f2bf(float x) {
  __hip_bfloat16 h = __float2bfloat16(x);  // RNE
  return *reinterpret_cast<ushort*>(&h);
}

// XCD-aligned swizzle: all 8 tiles of batch b land on XCD (b&7) so St[b]
// stays in one XCD's private L2 across phase A (write) and phase B (read).
__device__ __forceinline__ void swz(int Wd, int& b, int& t0) {
  const int x = Wd & 7, y = Wd >> 3;
  b  = ((y >> 3) << 3) | x;
  t0 = (y & 7) * 32;
}

// ---------------------------------------------------------------------------
// Single cooperative kernel: 3 phases separated by grid.sync().
//   A: St[b][f][m] = bf16((input_crop @ W)^T)   (+ beta-fill non-crop out)
//   B: Ocrop[b][n][f] = adj_crop[b][n][:] @ S[b][:][f]
//   C: BN stats over batch + normalize -> out crop rows
// smem union: A = wt(34816)+ain(8704) = 43520 B (max);
//             B = adt(16896)+stl(18432) = 35328 B; C = 2560 B.
// LDS 43.5KB -> 3 blocks/CU capacity = 768 >= 512 grid (co-residency slack).
// ---------------------------------------------------------------------------
__global__ __launch_bounds__(256, 2) void fused_all(
    const float* __restrict__ input, const float* __restrict__ adj,
    const float* __restrict__ W, const float* __restrict__ gamma,
    const float* __restrict__ beta, float* __restrict__ out,
    ushort* __restrict__ St, float* __restrict__ Ocrop) {
  __shared__ __align__(16) char smem[43520];
  const int tid = threadIdx.x;
  int b, t0;
  swz(blockIdx.x, b, t0);
  const int l = tid & 63, w = tid >> 6;
  const int lr = l & 15, lg = l >> 4;
  cg::grid_group grid = cg::this_grid();

  // ===== Phase A: support GEMM =====
  {
    ushort (*wt)[136]  = reinterpret_cast<ushort (*)[136]>(smem);          // [128][136]
    ushort (*ain)[136] = reinterpret_cast<ushort (*)[136]>(smem + 34816);  // [32][136]
    const float* inb = input + ((size_t)b * NADJ + CROP0 + t0) * F;
    // stage W^T (coalesced reads; 128B-contiguous ushort LDS writes)
    {
      const int i0 = tid & 63;
      const int fq = (tid >> 6) * 32;
#pragma unroll
      for (int ih = 0; ih < 2; ++ih) {
        const int i = i0 + ih * 64;
        const float* wr = &W[(size_t)i * F + fq];
        float4 v[8];
#pragma unroll
        for (int q = 0; q < 8; ++q)
          v[q] = reinterpret_cast<const float4*>(wr)[q];
#pragma unroll
        for (int q = 0; q < 8; ++q) {
          wt[fq + q * 4 + 0][i] = f2bf(v[q].x);
          wt[fq + q * 4 + 1][i] = f2bf(v[q].y);
          wt[fq + q * 4 + 2][i] = f2bf(v[q].z);
          wt[fq + q * 4 + 3][i] = f2bf(v[q].w);
        }
      }
    }
    for (int idx = tid; idx < 32 * 32; idx += 256) {
      const int ml = idx >> 5, c4 = (idx & 31) * 4;
      const float4 v =
          *reinterpret_cast<const float4*>(&inb[(size_t)ml * F + c4]);
      *reinterpret_cast<ushort4*>(&ain[ml][c4]) =
          make_ushort4(f2bf(v.x), f2bf(v.y), f2bf(v.z), f2bf(v.w));
    }
    __syncthreads();

    const int msub = (w & 1) * 16;
    const int f0   = (w >> 1) * 64;
    f32x4 acc[4] = {};
#pragma unroll
    for (int ks = 0; ks < 4; ++ks) {
      const int k0 = ks * 32 + lg * 8;
      const short8 av = *reinterpret_cast<const short8*>(&ain[msub + lr][k0]);
#pragma unroll
      for (int fi = 0; fi < 4; ++fi) {
        const short8 bv =
            *reinterpret_cast<const short8*>(&wt[f0 + fi * 16 + lr][k0]);
        acc[fi] =
            __builtin_amdgcn_mfma_f32_16x16x32_bf16(av, bv, acc[fi], 0, 0, 0);
      }
    }
#pragma unroll
    for (int fi = 0; fi < 4; ++fi) {
      const int f = f0 + fi * 16 + lr;
      *reinterpret_cast<ushort4*>(
          &St[((size_t)b * F + f) * CN + t0 + msub + lg * 4]) =
          make_ushort4(f2bf(acc[fi][0]), f2bf(acc[fi][1]), f2bf(acc[fi][2]),
                       f2bf(acc[fi][3]));
    }
    // beta-fill non-crop rows of out (independent work)
    const int gid = blockIdx.x * 256 + tid;
#pragma unroll
    for (int q = 0; q < 4; ++q) {
      const int g2 = gid + q * 131072;
      const int c4 = (g2 & 31) * 4;
      const int rr = (g2 >> 5) & 255;
      const int bb = g2 >> 13;
      const int n  = rr < 128 ? rr : rr + 256;
      const float4 bv =
          *reinterpret_cast<const float4*>(&beta[(size_t)n * F + c4]);
      *reinterpret_cast<float4*>(&out[((size_t)bb * NADJ + n) * F + c4]) = bv;
    }
  }

  // pre-issue phase-B adj tile loads: independent of phase A results, so
  // their HBM latency hides under the grid barrier wait
  const int ar = tid >> 6;
  const int ac = (tid & 63) * 4;
  const float* adjb = adj + ((size_t)b * NADJ + CROP0 + t0) * NADJ + CROP0;
  float4 areg[8];
#pragma unroll
  for (int q = 0; q < 8; ++q)
    areg[q] = *reinterpret_cast<const float4*>(
        &adjb[(size_t)(ar + q * 4) * NADJ + ac]);

  grid.sync();

  // ===== Phase B: aggregate GEMM (single-LDS-buffer, reg-staged chunks) ====
  {
    ushort (*adt)[264] = reinterpret_cast<ushort (*)[264]>(smem);  // [32][264]
    ushort (*stl)[72] = reinterpret_cast<ushort (*)[72]>(smem + 16896);  // [128][72]
    const ushort* Stb = St + (size_t)b * F * CN;
    const int sr = tid >> 3;       // 0..31
    const int sc = (tid & 7) * 8;  // 16B col
    uint4 sreg[4];
#pragma unroll
    for (int j = 0; j < 4; ++j)
      sreg[j] = *reinterpret_cast<const uint4*>(
          &Stb[(size_t)(sr + j * 32) * CN + sc]);
#pragma unroll
    for (int q = 0; q < 8; ++q)
      *reinterpret_cast<ushort4*>(&adt[ar + q * 4][ac]) =
          make_ushort4(f2bf(areg[q].x), f2bf(areg[q].y), f2bf(areg[q].z),
                       f2bf(areg[q].w));
#pragma unroll
    for (int j = 0; j < 4; ++j)
      *reinterpret_cast<uint4*>(&stl[sr + j * 32][sc]) = sreg[j];
    __syncthreads();

    const int nsub = (w & 1) * 16;
    const int f0   = (w >> 1) * 64;
    f32x4 acc[4] = {};
    for (int c = 0; c < 4; ++c) {
      uint4 nreg[4];
      if (c < 3) {  // reg-stage next chunk (regs are the second buffer)
#pragma unroll
        for (int j = 0; j < 4; ++j)
          nreg[j] = *reinterpret_cast<const uint4*>(
              &Stb[(size_t)(sr + j * 32) * CN + (c + 1) * 64 + sc]);
      }
#pragma unroll
      for (int ks = 0; ks < 2; ++ks) {
        const int kl = ks * 32 + lg * 8;
        const short8 av =
            *reinterpret_cast<const short8*>(&adt[nsub + lr][c * 64 + kl]);
#pragma unroll
        for (int fi = 0; fi < 4; ++fi) {
          const short8 bv =
              *reinterpret_cast<const short8*>(&stl[f0 + fi * 16 + lr][kl]);
          acc[fi] = __builtin_amdgcn_mfma_f32_16x16x32_bf16(av, bv, acc[fi],
                                                            0, 0, 0);
        }
      }
      if (c < 3) {
        __syncthreads();
#pragma unroll
        for (int j = 0; j < 4; ++j)
          *reinterpret_cast<uint4*>(&stl[sr + j * 32][sc]) = nreg[j];
        __syncthreads();
      }
    }
#pragma unroll
    for (int fi = 0; fi < 4; ++fi) {
      const int f = f0 + fi * 16 + lr;
      const int n = t0 + nsub + lg * 4;
#pragma unroll
      for (int r = 0; r < 4; ++r)
        Ocrop[((size_t)b * CN + n + r) * F + f] = acc[fi][r];
    }
  }

  grid.sync();

  // ===== Phase C: BN stats + normalize crop rows =====
  {
    float* s_l  = reinterpret_cast<float*>(smem);
    float* s2_l = s_l + 256;
    float* m_l  = s2_l + 256;
    float* r_l  = m_l + 64;
    const int jl = l, bg = w;
    const int j  = blockIdx.x * 64 + jl;  // 0..32767 = nl*128+f
    const int nl = j >> 7, f = j & 127;
    const int nf = (CROP0 + nl) * F + f;
    const float* p = Ocrop + (size_t)j + (size_t)bg * 16 * CN * F;
    float x[16];
    float s = 0.f, s2 = 0.f;
#pragma unroll
    for (int bb = 0; bb < 16; ++bb) {
      x[bb] = p[(size_t)bb * CN * F];
      s += x[bb];
      s2 += x[bb] * x[bb];
    }
    s_l[tid]  = s;
    s2_l[tid] = s2;
    __syncthreads();
    if (tid < 64) {
      s  = s_l[jl] + s_l[64 + jl] + s_l[128 + jl] + s_l[192 + jl];
      s2 = s2_l[jl] + s2_l[64 + jl] + s2_l[128 + jl] + s2_l[192 + jl];
      const float mean = s * (1.f / BATCH);
      const float var  = s2 * (1.f / BATCH) - mean * mean;
      m_l[jl] = mean;
      r_l[jl] = rsqrtf(var + BN_EPS);
    }
    __syncthreads();
    const float mean = m_l[jl];
    const float a    = r_l[jl] * gamma[nf];
    const float c    = beta[nf] - mean * a;
#pragma unroll
    for (int bb = 0; bb < 16; ++bb)
      out[(size_t)nf + (size_t)(bg * 16 + bb) * NADJ * F] = x[bb] * a + c;
  }
}

extern "C" void kernel_launch(void* const* d_in, const int* in_sizes, int n_in,
                              void* d_out, int out_size, void* d_ws,
                              size_t ws_size, hipStream_t stream) {
  const float* input = (const float*)d_in[0];
  const float* adj   = (const float*)d_in[1];
  const float* W     = (const float*)d_in[2];
  const float* gamma = (const float*)d_in[3];
  const float* beta  = (const float*)d_in[4];
  float* out = (float*)d_out;

  ushort* St    = (ushort*)d_ws;                            // 4 MB
  float*  Ocrop = (float*)((char*)d_ws + 4 * 1024 * 1024);  // 8.4 MB

  void* kargs[] = {(void*)&input, (void*)&adj, (void*)&W, (void*)&gamma,
                   (void*)&beta,  (void*)&out, (void*)&St, (void*)&Ocrop};
  hipLaunchCooperativeKernel((void*)fused_all, dim3(512), dim3(256), kargs,
                             0, stream);
}

// Round 10
// 32.602 us; speedup vs baseline: 4.6916x; 4.6916x over previous
//
#include <hip/hip_runtime.h>
#include <hip/hip_bf16.h>

#define BATCH 64
#define NADJ  512
#define F     128
#define CROP0 128
#define CROP1 384
#define CN    256
#define BN_EPS 1e-5f

typedef __attribute__((ext_vector_type(8))) short short8;
typedef __attribute__((ext_vector_type(4))) float f32x4;

__device__ __forceinline__ ushort f2bf(float x) {
  __hip_bfloat16 h = __float2bfloat16(x);  // RNE
  return *reinterpret_cast<ushort*>(&h);
}

__device__ __forceinline__ short8 cvt8(const float4 a, const float4 b) {
  short8 r;
  r[0] = (short)f2bf(a.x); r[1] = (short)f2bf(a.y);
  r[2] = (short)f2bf(a.z); r[3] = (short)f2bf(a.w);
  r[4] = (short)f2bf(b.x); r[5] = (short)f2bf(b.y);
  r[6] = (short)f2bf(b.z); r[7] = (short)f2bf(b.w);
  return r;
}

// XCD-aligned swizzle: all 8 tiles of batch b land on XCD (b&7) so St[b]
// stays in one XCD's private L2 across K1 (write) and K2 (read).
__device__ __forceinline__ void swz(int Wd, int& b, int& sub) {
  const int x = Wd & 7, y = Wd >> 3;
  b   = ((y >> 3) << 3) | x;
  sub = y & 7;
}

// ---------------------------------------------------------------------------
// K1: St[b][f][m] = bf16( (input_crop @ W)^T ), m-tile 32 per block.
// Also beta-fills the non-crop rows of out (K1 has idle latency slots; free).
// ---------------------------------------------------------------------------
__global__ __launch_bounds__(256) void support_k(
    const float* __restrict__ input, const float* __restrict__ W,
    ushort* __restrict__ St, float* __restrict__ out,
    const float* __restrict__ beta) {
  int b, sub;
  swz(blockIdx.x, b, sub);
  const int m0 = sub * 32;
  __shared__ ushort wt[128][136];  // W^T [f][i]
  __shared__ ushort ain[32][136];  // input tile [m][i]
  const int tid = threadIdx.x;
  const float* inb = input + ((size_t)b * NADJ + CROP0 + m0) * F;

  // stage W^T: thread covers i=(tid&63)+{0,64}, f=(tid>>6)*32..+32
  {
    const int i0 = tid & 63;
    const int fq = (tid >> 6) * 32;
#pragma unroll
    for (int ih = 0; ih < 2; ++ih) {
      const int i = i0 + ih * 64;
      const float* wr = &W[(size_t)i * F + fq];
      float4 v[8];
#pragma unroll
      for (int q = 0; q < 8; ++q)
        v[q] = reinterpret_cast<const float4*>(wr)[q];
#pragma unroll
      for (int q = 0; q < 8; ++q) {
        wt[fq + q * 4 + 0][i] = f2bf(v[q].x);
        wt[fq + q * 4 + 1][i] = f2bf(v[q].y);
        wt[fq + q * 4 + 2][i] = f2bf(v[q].z);
        wt[fq + q * 4 + 3][i] = f2bf(v[q].w);
      }
    }
  }
  for (int idx = tid; idx < 32 * 32; idx += 256) {
    const int ml = idx >> 5, c4 = (idx & 31) * 4;
    const float4 v =
        *reinterpret_cast<const float4*>(&inb[(size_t)ml * F + c4]);
    *reinterpret_cast<ushort4*>(&ain[ml][c4]) =
        make_ushort4(f2bf(v.x), f2bf(v.y), f2bf(v.z), f2bf(v.w));
  }
  __syncthreads();

  const int l = tid & 63, w = tid >> 6;
  const int lr = l & 15, lg = l >> 4;
  const int msub = (w & 1) * 16;
  const int f0   = (w >> 1) * 64;
  f32x4 acc[4] = {};
#pragma unroll
  for (int ks = 0; ks < 4; ++ks) {
    const int k0 = ks * 32 + lg * 8;
    const short8 av = *reinterpret_cast<const short8*>(&ain[msub + lr][k0]);
#pragma unroll
    for (int fi = 0; fi < 4; ++fi) {
      const short8 bv =
          *reinterpret_cast<const short8*>(&wt[f0 + fi * 16 + lr][k0]);
      acc[fi] =
          __builtin_amdgcn_mfma_f32_16x16x32_bf16(av, bv, acc[fi], 0, 0, 0);
    }
  }
#pragma unroll
  for (int fi = 0; fi < 4; ++fi) {
    const int f = f0 + fi * 16 + lr;
    *reinterpret_cast<ushort4*>(
        &St[((size_t)b * F + f) * CN + m0 + msub + lg * 4]) =
        make_ushort4(f2bf(acc[fi][0]), f2bf(acc[fi][1]), f2bf(acc[fi][2]),
                     f2bf(acc[fi][3]));
  }

  // beta-fill non-crop rows of out
  const int gid = blockIdx.x * 256 + tid;
#pragma unroll
  for (int q = 0; q < 4; ++q) {
    const int g2 = gid + q * 131072;
    const int c4 = (g2 & 31) * 4;
    const int rr = (g2 >> 5) & 255;
    const int bb = g2 >> 13;
    const int n  = rr < 128 ? rr : rr + 256;
    const float4 bv =
        *reinterpret_cast<const float4*>(&beta[(size_t)n * F + c4]);
    *reinterpret_cast<float4*>(&out[((size_t)bb * NADJ + n) * F + c4]) = bv;
  }
}

// ---------------------------------------------------------------------------
// K2: Ocrop[b][n][f] = adj_crop[b][n][:] @ S[b][:][f].
// Zero LDS, zero barriers: wave-owned 32n x 32f tile, K=256 unrolled.
// Waves in a block split n (no duplicated adj reads); ks order rotated per
// wave to de-correlate the load burst across L2 channels. All loads are
// independent -> waves de-synchronize and cover each other's stalls.
// ---------------------------------------------------------------------------
__global__ __launch_bounds__(256) void aggregate_k(
    const float* __restrict__ adj, const ushort* __restrict__ St,
    float* __restrict__ Ocrop) {
  int b, sub;
  swz(blockIdx.x, b, sub);
  const int nh = sub >> 2;      // n-half (128 rows)
  const int ft = sub & 3;       // f-tile (32 f)
  const int w  = threadIdx.x >> 6;
  const int l  = threadIdx.x & 63;
  const int lr = l & 15, lg = l >> 4;
  const int n0 = nh * 128 + w * 32;
  const int f0 = ft * 32;

  const float*  adjb = adj + ((size_t)b * NADJ + CROP0) * NADJ + CROP0;
  const ushort* Stb  = St + (size_t)b * F * CN;
  const float*  a0 = adjb + (size_t)(n0 + lr) * NADJ;
  const float*  a1 = adjb + (size_t)(n0 + 16 + lr) * NADJ;
  const ushort* s0 = Stb + (size_t)(f0 + lr) * CN;
  const ushort* s1 = Stb + (size_t)(f0 + 16 + lr) * CN;

  f32x4 acc[2][2] = {};
#pragma unroll
  for (int ks = 0; ks < 8; ++ks) {
    const int k0 = (((ks + 2 * w) & 7) * 32) + lg * 8;  // per-wave stagger
    const float4 x00 = *reinterpret_cast<const float4*>(&a0[k0]);
    const float4 x01 = *reinterpret_cast<const float4*>(&a0[k0 + 4]);
    const float4 x10 = *reinterpret_cast<const float4*>(&a1[k0]);
    const float4 x11 = *reinterpret_cast<const float4*>(&a1[k0 + 4]);
    const short8 b0 = *reinterpret_cast<const short8*>(&s0[k0]);
    const short8 b1 = *reinterpret_cast<const short8*>(&s1[k0]);
    const short8 av0 = cvt8(x00, x01);
    const short8 av1 = cvt8(x10, x11);
    acc[0][0] =
        __builtin_amdgcn_mfma_f32_16x16x32_bf16(av0, b0, acc[0][0], 0, 0, 0);
    acc[0][1] =
        __builtin_amdgcn_mfma_f32_16x16x32_bf16(av0, b1, acc[0][1], 0, 0, 0);
    acc[1][0] =
        __builtin_amdgcn_mfma_f32_16x16x32_bf16(av1, b0, acc[1][0], 0, 0, 0);
    acc[1][1] =
        __builtin_amdgcn_mfma_f32_16x16x32_bf16(av1, b1, acc[1][1], 0, 0, 0);
  }

#pragma unroll
  for (int mi = 0; mi < 2; ++mi)
#pragma unroll
    for (int fi = 0; fi < 2; ++fi) {
      const int f = f0 + fi * 16 + lr;
      const int n = n0 + mi * 16 + lg * 4;
#pragma unroll
      for (int r = 0; r < 4; ++r)
        Ocrop[((size_t)b * CN + n + r) * F + f] = acc[mi][fi][r];
    }
}

// ---------------------------------------------------------------------------
// K3: BN stats + normalize from dense Ocrop -> out crop rows.
// ---------------------------------------------------------------------------
__global__ __launch_bounds__(256) void bn_crop(
    const float* __restrict__ Ocrop, float* __restrict__ out,
    const float* __restrict__ gamma, const float* __restrict__ beta) {
  __shared__ float s_l[256], s2_l[256], m_l[64], r_l[64];
  const int tid = threadIdx.x;
  const int jl = tid & 63, bg = tid >> 6;
  const int j  = blockIdx.x * 64 + jl;  // 0..32767 = nl*128+f
  const int nl = j >> 7, f = j & 127;
  const int nf = (CROP0 + nl) * F + f;
  const float* p = Ocrop + (size_t)j + (size_t)bg * 16 * CN * F;

  float x[16];
  float s = 0.f, s2 = 0.f;
#pragma unroll
  for (int bb = 0; bb < 16; ++bb) {
    x[bb] = p[(size_t)bb * CN * F];
    s += x[bb];
    s2 += x[bb] * x[bb];
  }
  s_l[tid]  = s;
  s2_l[tid] = s2;
  __syncthreads();
  if (tid < 64) {
    s  = s_l[jl] + s_l[64 + jl] + s_l[128 + jl] + s_l[192 + jl];
    s2 = s2_l[jl] + s2_l[64 + jl] + s2_l[128 + jl] + s2_l[192 + jl];
    const float mean = s * (1.f / BATCH);
    const float var  = s2 * (1.f / BATCH) - mean * mean;
    m_l[jl] = mean;
    r_l[jl] = rsqrtf(var + BN_EPS);
  }
  __syncthreads();
  const float mean = m_l[jl];
  const float a    = r_l[jl] * gamma[nf];
  const float c    = beta[nf] - mean * a;
#pragma unroll
  for (int bb = 0; bb < 16; ++bb)
    out[(size_t)nf + (size_t)(bg * 16 + bb) * NADJ * F] = x[bb] * a + c;
}

extern "C" void kernel_launch(void* const* d_in, const int* in_sizes, int n_in,
                              void* d_out, int out_size, void* d_ws,
                              size_t ws_size, hipStream_t stream) {
  const float* input = (const float*)d_in[0];
  const float* adj   = (const float*)d_in[1];
  const float* W     = (const float*)d_in[2];
  const float* gamma = (const float*)d_in[3];
  const float* beta  = (const float*)d_in[4];
  float* out = (float*)d_out;

  ushort* St    = (ushort*)d_ws;                            // 4 MB
  float*  Ocrop = (float*)((char*)d_ws + 4 * 1024 * 1024);  // 8.4 MB

  support_k<<<512, 256, 0, stream>>>(input, W, St, out, beta);
  aggregate_k<<<512, 256, 0, stream>>>(adj, St, Ocrop);
  bn_crop<<<512, 256, 0, stream>>>(Ocrop, out, gamma, beta);
}